// Round 4
// baseline (432.945 us; speedup 1.0000x reference)
//
#include <hip/hip_runtime.h>
#include <math.h>

typedef __bf16 bf16;
typedef __bf16 bf16x8 __attribute__((ext_vector_type(8)));
typedef __bf16 bf16x4 __attribute__((ext_vector_type(4)));
typedef float f32x4 __attribute__((ext_vector_type(4)));

constexpr int cB = 256, cN = 256, cF = 128, cO = 256;
constexpr int BN = cB * cN;
constexpr float D2_FLOOR = 1e-12f;
constexpr float EPS_F = 1.401298464324817e-45f;  // np.spacing(float32(0))

// ---------------- workspace byte offsets ----------------
constexpr size_t OFF_XC  = 0;                                   // bf16 [BN][512]
constexpr size_t OFF_XW  = OFF_XC + (size_t)BN * 512 * 2;       // bf16 [BN][128]
constexpr size_t OFF_X0T = OFF_XW + (size_t)BN * 128 * 2;       // bf16 [B][128][256]
constexpr size_t OFF_X1T = OFF_X0T + (size_t)cB * cF * cN * 2;
constexpr size_t OFF_X2T = OFF_X1T + (size_t)cB * cF * cN * 2;
constexpr size_t OFF_LB  = OFF_X2T + (size_t)cB * cF * cN * 2;  // bf16 [B][256][256]
constexpr size_t OFF_WT  = OFF_LB + (size_t)cB * cN * cN * 2;   // bf16 [256][512]
constexpr size_t OFF_MT  = OFF_WT + 512 * 256 * 2;              // bf16 [128][128]
constexpr size_t OFF_SQ  = OFF_MT + 128 * 128 * 2;              // f32 [BN]

// Direct global->VGPR MFMA fragment load: p = base of 16-row granule, ld in elems.
// lane l supplies row (l&15) and 8-col slot 8*(l>>4) within the 32-wide k-slice k0.
__device__ __forceinline__ bf16x8 gfrag(const bf16* __restrict__ p, int ld,
                                        int lane, int k0) {
  return *(const bf16x8*)(p + (size_t)(lane & 15) * ld + k0 + 8 * (lane >> 4));
}

__device__ __forceinline__ f32x4 mfma(bf16x8 a, bf16x8 b, f32x4 c) {
  return __builtin_amdgcn_mfma_f32_16x16x32_bf16(a, b, c, 0, 0, 0);
}

// ---------------- k_prep: mask+convert; write xc[:,0:128] and x0T ----------------
__global__ __launch_bounds__(256) void k_prep(const float* __restrict__ x,
                                              const int* __restrict__ na_p,
                                              bf16* __restrict__ xc,
                                              bf16* __restrict__ x0T) {
  __shared__ __align__(16) bf16 T[64][132];
  int b = blockIdx.x >> 2, i0 = (blockIdx.x & 3) * 64;
  int tid = threadIdx.x;
  int na = na_p[b];
#pragma unroll
  for (int it = 0; it < 8; ++it) {
    int ir = it * 8 + (tid >> 5);
    int f0 = (tid & 31) * 4;
    int i = i0 + ir;
    float m = (i < na) ? 1.f : 0.f;
    float4 v = *(const float4*)(x + ((size_t)b * cN + i) * cF + f0);
    bf16x4 pk = {(bf16)(v.x * m), (bf16)(v.y * m), (bf16)(v.z * m), (bf16)(v.w * m)};
    *(bf16x4*)(xc + ((size_t)b * cN + i) * 512 + f0) = pk;
    *(bf16x4*)(&T[ir][f0]) = pk;
  }
  __syncthreads();
  int f = tid >> 1, half = tid & 1;
  bf16* od = x0T + ((size_t)b * cF + f) * cN + i0 + half * 32;
#pragma unroll
  for (int c = 0; c < 32; c += 4) {
    int ii = half * 32 + c;
    bf16x4 pk = {T[ii][f], T[ii + 1][f], T[ii + 2][f], T[ii + 3][f]};
    *(bf16x4*)(od + c) = pk;
  }
}

// ---------------- k_wt: Wt[o][k*128+f]=weight[f*4+k][o]; MT[g][f]=M_L[f][g] --------
__global__ __launch_bounds__(256) void k_wt(const float* __restrict__ wgt,
                                            const float* __restrict__ ML,
                                            bf16* __restrict__ Wt,
                                            bf16* __restrict__ MT) {
  int id = blockIdx.x * 256 + threadIdx.x;
  if (id < 512 * 256) {
    int o = id >> 9, d = id & 511;
    int k = d >> 7, f = d & 127;
    Wt[id] = (bf16)wgt[(f * 4 + k) * 256 + o];
  } else {
    int id2 = id - 512 * 256;
    if (id2 < 128 * 128) {
      int g = id2 >> 7, f = id2 & 127;
      MT[id2] = (bf16)ML[f * 128 + g];
    }
  }
}

// ---------------- k_xw2: xw = x0m @ M_L, fused sq (row sumsq of bf16 xw) ----------
__global__ __launch_bounds__(256, 2) void k_xw2(const bf16* __restrict__ xc,
                                                const bf16* __restrict__ MT,
                                                bf16* __restrict__ xw,
                                                float* __restrict__ sq) {
  __shared__ float sqb[128];
  int tid = threadIdx.x, wid = tid >> 6, lane = tid & 63;
  int r0 = blockIdx.x * 128;
  const bf16* A = xc + (size_t)r0 * 512;
  const bf16* Bg = MT + (size_t)(wid * 32) * 128;
  f32x4 acc[8][2] = {};
#pragma unroll
  for (int ks = 0; ks < 4; ++ks) {
    int k0 = ks * 32;
    bf16x8 b0 = gfrag(Bg, 128, lane, k0);
    bf16x8 b1 = gfrag(Bg + 16 * 128, 128, lane, k0);
#pragma unroll
    for (int mf = 0; mf < 8; ++mf) {
      bf16x8 a = gfrag(A + (size_t)mf * 16 * 512, 512, lane, k0);
      acc[mf][0] = mfma(a, b0, acc[mf][0]);
      acc[mf][1] = mfma(a, b1, acc[mf][1]);
    }
  }
  if (tid < 128) sqb[tid] = 0.f;
  __syncthreads();
  int hi = lane >> 4, il = lane & 15;
#pragma unroll
  for (int mf = 0; mf < 8; ++mf) {
#pragma unroll
    for (int r = 0; r < 4; ++r) {
      int row = r0 + mf * 16 + 4 * hi + r;
      float s = 0.f;
#pragma unroll
      for (int nf = 0; nf < 2; ++nf) {
        bf16 v = (bf16)acc[mf][nf][r];
        xw[(size_t)row * cF + wid * 32 + nf * 16 + il] = v;
        float f = (float)v;
        s = fmaf(f, f, s);
      }
      s += __shfl_xor(s, 1); s += __shfl_xor(s, 2);
      s += __shfl_xor(s, 4); s += __shfl_xor(s, 8);
      if (il == 0) atomicAdd(&sqb[mf * 16 + 4 * hi + r], s);
    }
  }
  __syncthreads();
  if (tid < 128) sq[r0 + tid] = sqb[tid];
}

// ---------------- k_gramL: Gram -> W(regs) -> deg -> dinv -> llearn + Lb ----------
__global__ __launch_bounds__(512, 2) void k_gramL(const bf16* __restrict__ xw,
                                                  const float* __restrict__ sq,
                                                  const float* __restrict__ lap,
                                                  const int* __restrict__ na_p,
                                                  bf16* __restrict__ Lb,
                                                  float* __restrict__ llearn) {
  __shared__ float lsq[256];
  __shared__ float deg[256];
  __shared__ float dinv[256];
  int b = blockIdx.x, tid = threadIdx.x, wid = tid >> 6, lane = tid & 63;
  int wm = wid >> 2, wn = wid & 3;
  if (tid < 256) { lsq[tid] = sq[b * cN + tid]; deg[tid] = 0.f; }
  const bf16* X = xw + (size_t)b * cN * cF;
  const bf16* Ag = X + (size_t)(wm * 128) * cF;
  const bf16* Bg = X + (size_t)(wn * 64) * cF;
  f32x4 acc[8][4] = {};
#pragma unroll
  for (int ks = 0; ks < 4; ++ks) {
    int k0 = ks * 32;
    bf16x8 bb[4];
#pragma unroll
    for (int nf = 0; nf < 4; ++nf) bb[nf] = gfrag(Bg + (size_t)nf * 16 * cF, cF, lane, k0);
#pragma unroll
    for (int mf = 0; mf < 8; ++mf) {
      bf16x8 a = gfrag(Ag + (size_t)mf * 16 * cF, cF, lane, k0);
#pragma unroll
      for (int nf = 0; nf < 4; ++nf) acc[mf][nf] = mfma(a, bb[nf], acc[mf][nf]);
    }
  }
  __syncthreads();   // lsq/deg init complete
  int na = na_p[b];
  int hi = lane >> 4, il = lane & 15;
#pragma unroll
  for (int mf = 0; mf < 8; ++mf) {
#pragma unroll
    for (int r = 0; r < 4; ++r) {
      int i = wm * 128 + mf * 16 + 4 * hi + r;
      float sqi = lsq[i];
      bool mi = i < na;
      float rs = 0.f;
#pragma unroll
      for (int nf = 0; nf < 4; ++nf) {
        int j = wn * 64 + nf * 16 + il;
        float w = 0.f;
        if (mi && j < na && i != j) {
          float d2 = fmaxf(sqi + lsq[j] - 2.f * acc[mf][nf][r], D2_FLOOR);
          w = __expf(-sqrtf(d2));
        }
        acc[mf][nf][r] = w;
        rs += w;
      }
      rs += __shfl_xor(rs, 1); rs += __shfl_xor(rs, 2);
      rs += __shfl_xor(rs, 4); rs += __shfl_xor(rs, 8);
      if (il == 0) atomicAdd(&deg[i], rs);
    }
  }
  __syncthreads();
  if (tid < 256) dinv[tid] = (tid < na) ? 1.f / sqrtf(deg[tid] + EPS_F) : 0.f;
  __syncthreads();
  const float* lapb = lap + (size_t)b * cN * cN;
  float* llb = llearn + (size_t)b * cN * cN;
  bf16* lbb = Lb + (size_t)b * cN * cN;
#pragma unroll
  for (int mf = 0; mf < 8; ++mf) {
#pragma unroll
    for (int r = 0; r < 4; ++r) {
      int i = wm * 128 + mf * 16 + 4 * hi + r;
      float di = dinv[i];
      float mi = (i < na) ? 1.f : 0.f;
#pragma unroll
      for (int nf = 0; nf < 4; ++nf) {
        int j = wn * 64 + nf * 16 + il;
        float v = -di * acc[mf][nf][r] * dinv[j];
        if (i == j && i < na) v += 1.f;
        size_t e = (size_t)i * cN + j;
        llb[e] = v;
        float mj = (j < na) ? 1.f : 0.f;
        lbb[e] = (bf16)(v + lapb[e] * mi * mj);
      }
    }
  }
}

// ---------------- k_cheb2: D[f][i]=(L@x)^T, no LDS, 2 blocks/mol ----------------
template<bool BETA, bool WRITE_T>
__global__ __launch_bounds__(256, 2) void k_cheb2(const bf16* __restrict__ xT,
                                                  const bf16* __restrict__ Lb,
                                                  const bf16* __restrict__ xppT,
                                                  bf16* __restrict__ xoutT,
                                                  bf16* __restrict__ xc, int kcol) {
  int bx = blockIdx.x;
  int b = bx >> 1, i0 = (bx & 1) * 128;
  int tid = threadIdx.x, wid = tid >> 6, lane = tid & 63;
  const bf16* A = xT + (size_t)b * cF * cN;
  const bf16* Bg = Lb + (size_t)b * cN * cN + (size_t)(i0 + wid * 32) * cN;
  f32x4 acc[8][2] = {};
#pragma unroll
  for (int ks = 0; ks < 8; ++ks) {
    int k0 = ks * 32;
    bf16x8 b0 = gfrag(Bg, cN, lane, k0);
    bf16x8 b1 = gfrag(Bg + 16 * cN, cN, lane, k0);
#pragma unroll
    for (int mf = 0; mf < 8; ++mf) {
      bf16x8 a = gfrag(A + (size_t)mf * 16 * cN, cN, lane, k0);
      acc[mf][0] = mfma(a, b0, acc[mf][0]);
      acc[mf][1] = mfma(a, b1, acc[mf][1]);
    }
  }
  int hi = lane >> 4, il = lane & 15;
#pragma unroll
  for (int mf = 0; mf < 8; ++mf) {
#pragma unroll
    for (int nf = 0; nf < 2; ++nf) {
      int i = i0 + wid * 32 + nf * 16 + il;
#pragma unroll
      for (int r = 0; r < 4; ++r) {
        int f = mf * 16 + 4 * hi + r;
        float v = acc[mf][nf][r];
        if (BETA) v = 2.f * v - (float)xppT[(size_t)b * cF * cN + (size_t)f * cN + i];
        bf16 bv = (bf16)v;
        if (WRITE_T) xoutT[(size_t)b * cF * cN + (size_t)f * cN + i] = bv;
        xc[((size_t)b * cN + i) * 512 + kcol + f] = bv;
      }
    }
  }
}

// ---------------- k_out2: out = relu((xc@Wt^T + bias)*mask), no LDS ----------------
__global__ __launch_bounds__(256, 2) void k_out2(const bf16* __restrict__ xc,
                                                 const bf16* __restrict__ Wt,
                                                 const float* __restrict__ bias,
                                                 const int* __restrict__ na_p,
                                                 float* __restrict__ out) {
  int tid = threadIdx.x, wid = tid >> 6, lane = tid & 63;
  int r0 = blockIdx.x * 128;
  const bf16* A = xc + (size_t)r0 * 512;
  const bf16* Bg = Wt + (size_t)(wid * 64) * 512;
  f32x4 acc[8][4] = {};
#pragma unroll 4
  for (int ks = 0; ks < 16; ++ks) {
    int k0 = ks * 32;
    bf16x8 bb[4];
#pragma unroll
    for (int nf = 0; nf < 4; ++nf) bb[nf] = gfrag(Bg + (size_t)nf * 16 * 512, 512, lane, k0);
#pragma unroll
    for (int mf = 0; mf < 8; ++mf) {
      bf16x8 a = gfrag(A + (size_t)mf * 16 * 512, 512, lane, k0);
#pragma unroll
      for (int nf = 0; nf < 4; ++nf) acc[mf][nf] = mfma(a, bb[nf], acc[mf][nf]);
    }
  }
  int na = na_p[r0 >> 8];
  int hi = lane >> 4, il = lane & 15;
#pragma unroll
  for (int nf = 0; nf < 4; ++nf) {
    int o = wid * 64 + nf * 16 + il;
    float bo = bias[o];
#pragma unroll
    for (int mf = 0; mf < 8; ++mf) {
#pragma unroll
      for (int r = 0; r < 4; ++r) {
        int row = r0 + mf * 16 + 4 * hi + r;
        float m = ((row & 255) < na) ? 1.f : 0.f;
        out[(size_t)row * cO + o] = fmaxf((acc[mf][nf][r] + bo) * m, 0.f);
      }
    }
  }
}

// ---------------- launcher ----------------
extern "C" void kernel_launch(void* const* d_in, const int* in_sizes, int n_in,
                              void* d_out, int out_size, void* d_ws, size_t ws_size,
                              hipStream_t stream) {
  const float* x    = (const float*)d_in[0];
  const float* lap  = (const float*)d_in[1];
  const int*   na   = (const int*)d_in[2];
  const float* M_L  = (const float*)d_in[3];
  const float* wgt  = (const float*)d_in[4];
  const float* bias = (const float*)d_in[5];

  float* out    = (float*)d_out;
  float* llearn = out + (size_t)BN * cO;

  char* ws = (char*)d_ws;
  bf16*  xc  = (bf16*)(ws + OFF_XC);
  bf16*  xw  = (bf16*)(ws + OFF_XW);
  bf16*  x0T = (bf16*)(ws + OFF_X0T);
  bf16*  x1T = (bf16*)(ws + OFF_X1T);
  bf16*  x2T = (bf16*)(ws + OFF_X2T);
  bf16*  Lb  = (bf16*)(ws + OFF_LB);
  bf16*  Wt  = (bf16*)(ws + OFF_WT);
  bf16*  MT  = (bf16*)(ws + OFF_MT);
  float* sqb = (float*)(ws + OFF_SQ);

  k_prep<<<dim3(1024), 256, 0, stream>>>(x, na, xc, x0T);
  k_wt<<<dim3(576), 256, 0, stream>>>(wgt, M_L, Wt, MT);
  k_xw2<<<dim3(512), 256, 0, stream>>>(xc, MT, xw, sqb);
  k_gramL<<<dim3(cB), 512, 0, stream>>>(xw, sqb, lap, na, Lb, llearn);
  k_cheb2<false, true><<<dim3(512), 256, 0, stream>>>(x0T, Lb, x0T, x1T, xc, 128);
  k_cheb2<true, true><<<dim3(512), 256, 0, stream>>>(x1T, Lb, x0T, x2T, xc, 256);
  k_cheb2<true, false><<<dim3(512), 256, 0, stream>>>(x2T, Lb, x1T, x2T, xc, 384);
  k_out2<<<dim3(512), 256, 0, stream>>>(xc, Wt, bias, na, out);
}

// Round 5
// 380.599 us; speedup vs baseline: 1.1375x; 1.1375x over previous
//
#include <hip/hip_runtime.h>
#include <math.h>

typedef __bf16 bf16;
typedef __bf16 bf16x8 __attribute__((ext_vector_type(8)));
typedef __bf16 bf16x4 __attribute__((ext_vector_type(4)));
typedef float f32x4 __attribute__((ext_vector_type(4)));

constexpr int cB = 256, cN = 256, cF = 128, cO = 256;
constexpr int BN = cB * cN;
constexpr float D2_FLOOR = 1e-12f;
constexpr float EPS_F = 1.401298464324817e-45f;  // np.spacing(float32(0))

// ---------------- workspace byte offsets ----------------
constexpr size_t OFF_XC  = 0;                                   // bf16 [BN][512]
constexpr size_t OFF_XW  = OFF_XC + (size_t)BN * 512 * 2;       // bf16 [BN][128]
constexpr size_t OFF_X0T = OFF_XW + (size_t)BN * 128 * 2;       // bf16 [B][128][256]
constexpr size_t OFF_LB  = OFF_X0T + (size_t)cB * cF * cN * 2;  // bf16 [B][256][256]
constexpr size_t OFF_WB  = OFF_LB + (size_t)cB * cN * cN * 2;   // bf16 [B][256][256]
constexpr size_t OFF_WT  = OFF_WB + (size_t)cB * cN * cN * 2;   // bf16 [256][512]
constexpr size_t OFF_MT  = OFF_WT + 512 * 256 * 2;              // bf16 [128][128]
constexpr size_t OFF_SQ  = OFF_MT + 128 * 128 * 2;              // f32 [BN]
constexpr size_t OFF_DEG = OFF_SQ + (size_t)BN * 4;             // f32 [BN]

// Direct global->VGPR MFMA fragment load: p = base of 16-row granule, ld in elems.
__device__ __forceinline__ bf16x8 gfrag(const bf16* __restrict__ p, int ld,
                                        int lane, int k0) {
  return *(const bf16x8*)(p + (size_t)(lane & 15) * ld + k0 + 8 * (lane >> 4));
}

__device__ __forceinline__ f32x4 mfma(bf16x8 a, bf16x8 b, f32x4 c) {
  return __builtin_amdgcn_mfma_f32_16x16x32_bf16(a, b, c, 0, 0, 0);
}

__device__ __forceinline__ void gll16(const void* g, void* l) {
  __builtin_amdgcn_global_load_lds((const __attribute__((address_space(1))) void*)g,
                                   (__attribute__((address_space(3))) void*)l, 16, 0, 0);
}

// ---------------- k_prep: mask+convert; write xc[:,0:128] and x0T ----------------
__global__ __launch_bounds__(256) void k_prep(const float* __restrict__ x,
                                              const int* __restrict__ na_p,
                                              bf16* __restrict__ xc,
                                              bf16* __restrict__ x0T) {
  __shared__ __align__(16) bf16 T[64][132];
  int b = blockIdx.x >> 2, i0 = (blockIdx.x & 3) * 64;
  int tid = threadIdx.x;
  int na = na_p[b];
#pragma unroll
  for (int it = 0; it < 8; ++it) {
    int ir = it * 8 + (tid >> 5);
    int f0 = (tid & 31) * 4;
    int i = i0 + ir;
    float m = (i < na) ? 1.f : 0.f;
    float4 v = *(const float4*)(x + ((size_t)b * cN + i) * cF + f0);
    bf16x4 pk = {(bf16)(v.x * m), (bf16)(v.y * m), (bf16)(v.z * m), (bf16)(v.w * m)};
    *(bf16x4*)(xc + ((size_t)b * cN + i) * 512 + f0) = pk;
    *(bf16x4*)(&T[ir][f0]) = pk;
  }
  __syncthreads();
  int f = tid >> 1, half = tid & 1;
  bf16* od = x0T + ((size_t)b * cF + f) * cN + i0 + half * 32;
#pragma unroll
  for (int c = 0; c < 32; c += 4) {
    int ii = half * 32 + c;
    bf16x4 pk = {T[ii][f], T[ii + 1][f], T[ii + 2][f], T[ii + 3][f]};
    *(bf16x4*)(od + c) = pk;
  }
}

// ---------------- k_wt: Wt[o][k*128+f]=weight[f*4+k][o]; MT[g][f]=M_L[f][g] --------
__global__ __launch_bounds__(256) void k_wt(const float* __restrict__ wgt,
                                            const float* __restrict__ ML,
                                            bf16* __restrict__ Wt,
                                            bf16* __restrict__ MT) {
  int id = blockIdx.x * 256 + threadIdx.x;
  if (id < 512 * 256) {
    int o = id >> 9, d = id & 511;
    int k = d >> 7, f = d & 127;
    Wt[id] = (bf16)wgt[(f * 4 + k) * 256 + o];
  } else {
    int id2 = id - 512 * 256;
    if (id2 < 128 * 128) {
      int g = id2 >> 7, f = id2 & 127;
      MT[id2] = (bf16)ML[f * 128 + g];
    }
  }
}

// ---------------- k_xw2: xw = x0m @ M_L, fused sq ----------------
__global__ __launch_bounds__(256, 2) void k_xw2(const bf16* __restrict__ xc,
                                                const bf16* __restrict__ MT,
                                                bf16* __restrict__ xw,
                                                float* __restrict__ sq) {
  __shared__ float sqb[128];
  int tid = threadIdx.x, wid = tid >> 6, lane = tid & 63;
  int r0 = blockIdx.x * 128;
  const bf16* A = xc + (size_t)r0 * 512;
  const bf16* Bg = MT + (size_t)(wid * 32) * 128;
  f32x4 acc[8][2] = {};
#pragma unroll
  for (int ks = 0; ks < 4; ++ks) {
    int k0 = ks * 32;
    bf16x8 b0 = gfrag(Bg, 128, lane, k0);
    bf16x8 b1 = gfrag(Bg + 16 * 128, 128, lane, k0);
#pragma unroll
    for (int mf = 0; mf < 8; ++mf) {
      bf16x8 a = gfrag(A + (size_t)mf * 16 * 512, 512, lane, k0);
      acc[mf][0] = mfma(a, b0, acc[mf][0]);
      acc[mf][1] = mfma(a, b1, acc[mf][1]);
    }
  }
  if (tid < 128) sqb[tid] = 0.f;
  __syncthreads();
  int hi = lane >> 4, il = lane & 15;
#pragma unroll
  for (int mf = 0; mf < 8; ++mf) {
#pragma unroll
    for (int r = 0; r < 4; ++r) {
      int row = r0 + mf * 16 + 4 * hi + r;
      float s = 0.f;
#pragma unroll
      for (int nf = 0; nf < 2; ++nf) {
        bf16 v = (bf16)acc[mf][nf][r];
        xw[(size_t)row * cF + wid * 32 + nf * 16 + il] = v;
        float f = (float)v;
        s = fmaf(f, f, s);
      }
      s += __shfl_xor(s, 1); s += __shfl_xor(s, 2);
      s += __shfl_xor(s, 4); s += __shfl_xor(s, 8);
      if (il == 0) atomicAdd(&sqb[mf * 16 + 4 * hi + r], s);
    }
  }
  __syncthreads();
  if (tid < 128) sq[r0 + tid] = sqb[tid];
}

// ---------------- k_gram2: per i-half Gram -> W bf16 + complete deg rows ----------
__global__ __launch_bounds__(512, 2) void k_gram2(const bf16* __restrict__ xw,
                                                  const float* __restrict__ sq,
                                                  const int* __restrict__ na_p,
                                                  bf16* __restrict__ Wb16,
                                                  float* __restrict__ deg) {
  __shared__ float lsq[256];
  __shared__ float degl[128];
  int bx = blockIdx.x;
  int b = bx >> 1, i0 = (bx & 1) * 128;
  int tid = threadIdx.x, wid = tid >> 6, lane = tid & 63;
  int wm = wid >> 2, wn = wid & 3;
  if (tid < 256) lsq[tid] = sq[b * cN + tid];
  if (tid < 128) degl[tid] = 0.f;
  const bf16* X = xw + (size_t)b * cN * cF;
  const bf16* Ag = X + (size_t)(i0 + wm * 64) * cF;
  const bf16* Bg = X + (size_t)(wn * 64) * cF;
  f32x4 acc[4][4] = {};
#pragma unroll
  for (int ks = 0; ks < 4; ++ks) {
    int k0 = ks * 32;
    bf16x8 bb[4];
#pragma unroll
    for (int nf = 0; nf < 4; ++nf) bb[nf] = gfrag(Bg + (size_t)nf * 16 * cF, cF, lane, k0);
#pragma unroll
    for (int mf = 0; mf < 4; ++mf) {
      bf16x8 a = gfrag(Ag + (size_t)mf * 16 * cF, cF, lane, k0);
#pragma unroll
      for (int nf = 0; nf < 4; ++nf) acc[mf][nf] = mfma(a, bb[nf], acc[mf][nf]);
    }
  }
  __syncthreads();
  int na = na_p[b];
  int hi = lane >> 4, il = lane & 15;
#pragma unroll
  for (int mf = 0; mf < 4; ++mf) {
#pragma unroll
    for (int r = 0; r < 4; ++r) {
      int i = i0 + wm * 64 + mf * 16 + 4 * hi + r;
      float sqi = lsq[i];
      bool mi = i < na;
      float rs = 0.f;
#pragma unroll
      for (int nf = 0; nf < 4; ++nf) {
        int j = wn * 64 + nf * 16 + il;
        float w = 0.f;
        if (mi && j < na && i != j) {
          float d2 = fmaxf(sqi + lsq[j] - 2.f * acc[mf][nf][r], D2_FLOOR);
          w = __expf(-sqrtf(d2));
        }
        Wb16[((size_t)b * cN + i) * cN + j] = (bf16)w;
        rs += w;
      }
      rs += __shfl_xor(rs, 1); rs += __shfl_xor(rs, 2);
      rs += __shfl_xor(rs, 4); rs += __shfl_xor(rs, 8);
      if (il == 0) atomicAdd(&degl[i - i0], rs);
    }
  }
  __syncthreads();
  if (tid < 128) deg[b * cN + i0 + tid] = degl[tid];
}

// ---------------- k_Lassm: elementwise L assembly (full occupancy) ----------------
__global__ __launch_bounds__(256) void k_Lassm(const bf16* __restrict__ Wb16,
                                               const float* __restrict__ deg,
                                               const float* __restrict__ lap,
                                               const int* __restrict__ na_p,
                                               bf16* __restrict__ Lb,
                                               float* __restrict__ llearn) {
  int tid = threadIdx.x;
  size_t e = ((size_t)blockIdx.x * 256 + tid) * 4;   // 1024 elems = 4 rows per block
  int b = (int)(e >> 16);
  int na = na_p[b];
  __shared__ float dinvl[256];
  if (tid < 256) dinvl[tid] = (tid < na) ? 1.f / sqrtf(deg[b * cN + tid] + EPS_F) : 0.f;
  __syncthreads();
  int j = (int)(e & 255);
  int i = (int)((e >> 8) & 255);
  bf16x4 w4 = *(const bf16x4*)(Wb16 + e);
  float4 lp = *(const float4*)(lap + e);
  float di = dinvl[i];
  float mi = (i < na) ? 1.f : 0.f;
  float4 ll;
  bf16x4 lo;
#pragma unroll
  for (int c = 0; c < 4; ++c) {
    int jj = j + c;
    float v = -di * (float)w4[c] * dinvl[jj];
    if (i == jj && i < na) v += 1.f;
    (&ll.x)[c] = v;
    float mj = (jj < na) ? 1.f : 0.f;
    lo[c] = (bf16)(v + (&lp.x)[c] * mi * mj);
  }
  *(float4*)(llearn + e) = ll;
  *(bf16x4*)(Lb + e) = lo;
}

// ---------------- k_cheb_f: all 3 Chebyshev steps, x-states in swizzled LDS -------
// LDS layout per buffer: xT[f][i] bf16, row stride 512B, byte ^= ((f&7)<<4).
__device__ __forceinline__ void cheb_step(const bf16* __restrict__ Lm,
                                          const char* Bsrc, const char* Ppp,
                                          char* Odst, bf16* __restrict__ xcm,
                                          int kcol, int wid, int lane, bool haspp,
                                          bool wlds) {
  int hi = lane >> 4, il = lane & 15;
  int i0w = wid * 32;
  f32x4 acc[2][8] = {};
#pragma unroll
  for (int ks = 0; ks < 8; ++ks) {
    int k0 = ks * 32;
    bf16x8 a0 = gfrag(Lm + (size_t)i0w * cN, cN, lane, k0);
    bf16x8 a1 = gfrag(Lm + (size_t)(i0w + 16) * cN, cN, lane, k0);
#pragma unroll
    for (int nf = 0; nf < 8; ++nf) {
      int f = nf * 16 + il;
      const char* p = Bsrc + f * 512 + ((64 * ks + 16 * hi) ^ ((il & 7) << 4));
      bf16x8 bb = *(const bf16x8*)p;
      acc[0][nf] = mfma(a0, bb, acc[0][nf]);
      acc[1][nf] = mfma(a1, bb, acc[1][nf]);
    }
  }
#pragma unroll
  for (int mf = 0; mf < 2; ++mf) {
    int ib = i0w + mf * 16 + 4 * hi;              // 4 consecutive i
#pragma unroll
    for (int nf = 0; nf < 8; ++nf) {
      int f = nf * 16 + il;
      int cb = (2 * ib) ^ ((il & 7) << 4);
      bf16x4 o;
      if (haspp) {
        bf16x4 pp = *(const bf16x4*)(Ppp + f * 512 + cb);
#pragma unroll
        for (int r = 0; r < 4; ++r) o[r] = (bf16)(2.f * acc[mf][nf][r] - (float)pp[r]);
      } else {
#pragma unroll
        for (int r = 0; r < 4; ++r) o[r] = (bf16)acc[mf][nf][r];
      }
      if (wlds) *(bf16x4*)(Odst + f * 512 + cb) = o;
#pragma unroll
      for (int r = 0; r < 4; ++r)
        xcm[(size_t)(ib + r) * 512 + kcol + f] = o[r];
    }
  }
}

__global__ __launch_bounds__(512, 1) void k_cheb_f(const bf16* __restrict__ x0T,
                                                   const bf16* __restrict__ Lb,
                                                   bf16* __restrict__ xc) {
  __shared__ __align__(16) char XB[2][65536];
  int b = blockIdx.x;
  int tid = threadIdx.x, wid = tid >> 6, lane = tid & 63;
  const bf16* Lm = Lb + (size_t)b * cN * cN;
  bf16* xcm = xc + (size_t)b * cN * 512;
  const char* src = (const char*)(x0T + (size_t)b * cF * cN);
  // load x0T (64KB) into XB[0], swizzled via pre-swizzled global source
#pragma unroll
  for (int it = 0; it < 8; ++it) {
    int beta = it * 8192 + tid * 16;
    int f = beta >> 9, c = beta & 511;
    gll16(src + f * 512 + (c ^ ((f & 7) << 4)), XB[0] + beta);
  }
  __syncthreads();
  cheb_step(Lm, XB[0], nullptr, XB[1], xcm, 128, wid, lane, false, true);  // x1
  __syncthreads();
  cheb_step(Lm, XB[1], XB[0], XB[0], xcm, 256, wid, lane, true, true);     // x2
  __syncthreads();
  cheb_step(Lm, XB[0], XB[1], nullptr, xcm, 384, wid, lane, true, false);  // x3
}

// ---------------- k_out2: out = relu((xc@Wt^T + bias)*mask), no LDS ----------------
__global__ __launch_bounds__(256, 2) void k_out2(const bf16* __restrict__ xc,
                                                 const bf16* __restrict__ Wt,
                                                 const float* __restrict__ bias,
                                                 const int* __restrict__ na_p,
                                                 float* __restrict__ out) {
  int tid = threadIdx.x, wid = tid >> 6, lane = tid & 63;
  int r0 = blockIdx.x * 128;
  const bf16* A = xc + (size_t)r0 * 512;
  const bf16* Bg = Wt + (size_t)(wid * 64) * 512;
  f32x4 acc[8][4] = {};
#pragma unroll 4
  for (int ks = 0; ks < 16; ++ks) {
    int k0 = ks * 32;
    bf16x8 bb[4];
#pragma unroll
    for (int nf = 0; nf < 4; ++nf) bb[nf] = gfrag(Bg + (size_t)nf * 16 * 512, 512, lane, k0);
#pragma unroll
    for (int mf = 0; mf < 8; ++mf) {
      bf16x8 a = gfrag(A + (size_t)mf * 16 * 512, 512, lane, k0);
#pragma unroll
      for (int nf = 0; nf < 4; ++nf) acc[mf][nf] = mfma(a, bb[nf], acc[mf][nf]);
    }
  }
  int na = na_p[r0 >> 8];
  int hi = lane >> 4, il = lane & 15;
#pragma unroll
  for (int nf = 0; nf < 4; ++nf) {
    int o = wid * 64 + nf * 16 + il;
    float bo = bias[o];
#pragma unroll
    for (int mf = 0; mf < 8; ++mf) {
#pragma unroll
      for (int r = 0; r < 4; ++r) {
        int row = r0 + mf * 16 + 4 * hi + r;
        float m = ((row & 255) < na) ? 1.f : 0.f;
        out[(size_t)row * cO + o] = fmaxf((acc[mf][nf][r] + bo) * m, 0.f);
      }
    }
  }
}

// ---------------- launcher ----------------
extern "C" void kernel_launch(void* const* d_in, const int* in_sizes, int n_in,
                              void* d_out, int out_size, void* d_ws, size_t ws_size,
                              hipStream_t stream) {
  const float* x    = (const float*)d_in[0];
  const float* lap  = (const float*)d_in[1];
  const int*   na   = (const int*)d_in[2];
  const float* M_L  = (const float*)d_in[3];
  const float* wgt  = (const float*)d_in[4];
  const float* bias = (const float*)d_in[5];

  float* out    = (float*)d_out;
  float* llearn = out + (size_t)BN * cO;

  char* ws = (char*)d_ws;
  bf16*  xc  = (bf16*)(ws + OFF_XC);
  bf16*  xw  = (bf16*)(ws + OFF_XW);
  bf16*  x0T = (bf16*)(ws + OFF_X0T);
  bf16*  Lb  = (bf16*)(ws + OFF_LB);
  bf16*  Wb  = (bf16*)(ws + OFF_WB);
  bf16*  Wt  = (bf16*)(ws + OFF_WT);
  bf16*  MT  = (bf16*)(ws + OFF_MT);
  float* sqb = (float*)(ws + OFF_SQ);
  float* deg = (float*)(ws + OFF_DEG);

  k_prep<<<dim3(1024), 256, 0, stream>>>(x, na, xc, x0T);
  k_wt<<<dim3(576), 256, 0, stream>>>(wgt, M_L, Wt, MT);
  k_xw2<<<dim3(512), 256, 0, stream>>>(xc, MT, xw, sqb);
  k_gram2<<<dim3(512), 512, 0, stream>>>(xw, sqb, na, Wb, deg);
  k_Lassm<<<dim3(16384), 256, 0, stream>>>(Wb, deg, lap, na, Lb, llearn);
  k_cheb_f<<<dim3(cB), 512, 0, stream>>>(x0T, Lb, xc);
  k_out2<<<dim3(512), 256, 0, stream>>>(xc, Wt, bias, na, out);
}